// Round 5
// baseline (91.696 us; speedup 1.0000x reference)
//
#include <hip/hip_runtime.h>

// Problem constants (fixed by reference): pred/target (8,3,224,224) fp32.
#define BINS   30
#define BATCH  8
#define NB     (BATCH * BINS)    // 240
#define ROW_N  150528            // 3*224*224 elements per batch row
#define ROW_N4 (ROW_N / 4)       // 37632 float4 per row
#define NROWS  16                // 2 inputs * 8 batches
#define BPR_A  8                 // blocks per row in fine-hist kernel -> 128 blocks

// exp(-0.5*u^2) = exp2(KU * u^2), u = (x-c)/delta = (x-c)*30
// KU = -0.5*log2(e);  KX = KU * 30^2  (argument in x-units)
#define KXF (-649.2627684000335f)
#define RAD (6.5f / 30.0f)       // truncate kernel at |u| > 6.5 (tail < 7e-10)

// ---- Phase A: linear-interpolated fine histogram per row ----------------
// Element x -> continuous pos q = x*F - 0.5; mass split between fine bins
// i0 = floor(q)+1 and i0+1 (fine bin i has center x_i = (i-0.5)/F).
// Row histogram has F+2 bins (edge bins catch x near 0 and 1).
__global__ __launch_bounds__(256) void hsim_fine_kernel(
    const float* __restrict__ pred,
    const float* __restrict__ target,
    float* __restrict__ fineg,       // [NROWS][F+2], pre-zeroed
    int lgF)
{
    const int F  = 1 << lgF;
    const int FW = F + 2;
    extern __shared__ float lh[];    // FW floats

    const int row       = blockIdx.x >> 3;       // BPR_A = 8
    const int chunk     = blockIdx.x & (BPR_A - 1);
    const int input_sel = row >> 3;              // 0 = pred, 1 = target
    const int batch     = row & 7;

    const float4* src4 =
        (const float4*)((input_sel ? target : pred) + (size_t)batch * ROW_N);

    for (int i = threadIdx.x; i < FW; i += 256) lh[i] = 0.0f;
    __syncthreads();

    const float Ff = (float)F;
    for (int i = chunk * 256 + threadIdx.x; i < ROW_N4; i += BPR_A * 256) {
        float4 v = src4[i];
        float xs[4] = { v.x, v.y, v.z, v.w };
#pragma unroll
        for (int k = 0; k < 4; ++k) {
            const float q  = fmaf(xs[k], Ff, -0.5f);
            const float fi = floorf(q);
            const float fr = q - fi;
            const int   i0 = (int)fi + 1;        // in [0, F]
            atomicAdd(&lh[i0],     1.0f - fr);
            atomicAdd(&lh[i0 + 1], fr);
        }
    }
    __syncthreads();

    float* grow = fineg + (size_t)row * FW;
    for (int i = threadIdx.x; i < FW; i += 256)
        atomicAdd(&grow[i], lh[i]);
}

// ---- Phase B: windowed Gaussian convolution + per-halfbatch score ------
// Grid: 16 blocks = (batch 0..7) x (half 0..1); each block does 15 bins,
// 16 threads per bin striding the fine window; both pred and target rows
// share the weights.
__global__ __launch_bounds__(256) void hsim_scorepart_kernel(
    const float* __restrict__ fineg, float* __restrict__ partials, int lgF)
{
    const int F  = 1 << lgF;
    const int FW = F + 2;
    const int batch = blockIdx.x >> 1;
    const int half  = blockIdx.x & 1;

    const float* fp = fineg + (size_t)batch * FW;
    const float* ft = fineg + (size_t)(batch + 8) * FW;

    const int t    = threadIdx.x;
    const int binl = t >> 4;         // 0..15 (15 used)
    const int sub  = t & 15;

    __shared__ float ssum;
    if (t == 0) ssum = 0.0f;
    __syncthreads();

    if (binl < 15) {
        const int   bin  = half * 15 + binl;
        const float c    = (bin + 0.5f) / 30.0f;
        const float Ff   = (float)F;
        const float invF = 1.0f / Ff;

        int ilo = (int)ceilf((c - RAD) * Ff + 0.5f);
        int ihi = (int)floorf((c + RAD) * Ff + 0.5f);
        ilo = max(ilo, 0);
        ihi = min(ihi, F + 1);

        float pw = 0.0f, tw = 0.0f;
        for (int f = ilo + sub; f <= ihi; f += 16) {
            const float x = ((float)f - 0.5f) * invF;   // fine-bin center
            const float d = x - c;
            const float e = __builtin_amdgcn_exp2f(KXF * d * d);
            pw = fmaf(e, fp[f], pw);
            tw = fmaf(e, ft[f], tw);
        }
#pragma unroll
        for (int off = 8; off >= 1; off >>= 1) {
            pw += __shfl_xor(pw, off, 64);
            tw += __shfl_xor(tw, off, 64);
        }
        if (sub == 0) {
            const float m  = fminf(pw, tw);
            const float pd = (pw == 0.0f) ? 1.0f : pw;
            atomicAdd(&ssum, m / pd);
        }
    }
    __syncthreads();
    if (t == 0) partials[blockIdx.x] = ssum;
}

// ---- Phase C: final sum --------------------------------------------------
__global__ __launch_bounds__(64) void hsim_final_kernel(
    const float* __restrict__ partials, float* __restrict__ out)
{
    const int t = threadIdx.x;
    float v = (t < 16) ? partials[t] : 0.0f;
#pragma unroll
    for (int off = 32; off >= 1; off >>= 1)
        v += __shfl_xor(v, off, 64);
    if (t == 0) out[0] = v * (1.0f / (float)NB);
}

extern "C" void kernel_launch(void* const* d_in, const int* in_sizes, int n_in,
                              void* d_out, int out_size, void* d_ws, size_t ws_size,
                              hipStream_t stream) {
    const float* pred   = (const float*)d_in[0];
    const float* target = (const float*)d_in[1];
    float*       fineg  = (float*)d_ws;
    float*       out    = (float*)d_out;

    // Pick fine resolution by available scratch (ws_size is fixed -> deterministic).
    int lgF = 12;                                                  // 263 KB
    if (ws_size < (size_t)NROWS * ((1 << 12) + 2) * 4 + 128) lgF = 10;  // 66 KB
    if (ws_size < (size_t)NROWS * ((1 << 10) + 2) * 4 + 128) lgF = 8;   // 16.6 KB
    const int FW = (1 << lgF) + 2;

    float* partials = fineg + (size_t)NROWS * FW;   // 16 floats

    hipMemsetAsync(fineg, 0, (size_t)NROWS * FW * sizeof(float), stream);
    hsim_fine_kernel<<<NROWS * BPR_A, 256, FW * sizeof(float), stream>>>(
        pred, target, fineg, lgF);
    hsim_scorepart_kernel<<<16, 256, 0, stream>>>(fineg, partials, lgF);
    hsim_final_kernel<<<1, 64, 0, stream>>>(partials, out);
}

// Round 6
// 37.091 us; speedup vs baseline: 2.4722x; 2.4722x over previous
//
#include <hip/hip_runtime.h>

// Problem constants (fixed by reference): pred/target (8,3,224,224) fp32.
#define BINS   30
#define BATCH  8
#define NB     (BATCH * BINS)    // 240
#define ROW_N  150528            // 3*224*224 elements per batch row
#define ROW_N4 (ROW_N / 4)       // 37632 float4 per row
#define NROWS  16                // 2 inputs * 8 batches
#define BPR_A  32                // 512 blocks = 2 blocks/CU

// Fixed-point scale for interpolation weights. Worst case ALL elements in one
// fine bin: 150528 * 16384 = 2.47e9 < 2^32 -> overflow-free for any data.
#define SCALEF     16384.0f
#define SCALEI     16384u
#define INV_SCALE  (1.0f / 16384.0f)

// exp(-0.5*((x-c)/delta)^2) = exp2(KXF*(x-c)^2), KXF = -0.5*log2(e)*900
#define KXF (-649.2627684000335f)
#define RAD (6.5f / 30.0f)       // truncate kernel at |u| > 6.5 (tail < 7e-10)

// ---- Phase A: linear-interpolated fine histogram (integer atomics) ------
__global__ __launch_bounds__(256) void hsim_fine_kernel(
    const float* __restrict__ pred,
    const float* __restrict__ target,
    unsigned int* __restrict__ fineg,    // [NROWS][F+2], pre-zeroed
    int lgF)
{
    const int F  = 1 << lgF;
    const int FW = F + 2;
    extern __shared__ unsigned int lh[];  // FW u32

    const int row       = blockIdx.x >> 5;          // BPR_A = 32
    const int chunk     = blockIdx.x & (BPR_A - 1);
    const int input_sel = row >> 3;                 // 0 = pred, 1 = target
    const int batch     = row & 7;

    const float4* src4 =
        (const float4*)((input_sel ? target : pred) + (size_t)batch * ROW_N);

    for (int i = threadIdx.x; i < FW; i += 256) lh[i] = 0u;
    __syncthreads();

    const float Ff = (float)F;
    for (int i = chunk * 256 + threadIdx.x; i < ROW_N4; i += BPR_A * 256) {
        float4 v = src4[i];
        float xs[4] = { v.x, v.y, v.z, v.w };
#pragma unroll
        for (int k = 0; k < 4; ++k) {
            const float q  = fmaf(xs[k], Ff, -0.5f);
            const float fi = floorf(q);
            const unsigned int w1 = (unsigned int)((q - fi) * SCALEF + 0.5f);
            const int i0 = (int)fi + 1;             // in [0, F]
            atomicAdd(&lh[i0],     SCALEI - w1);    // native ds_add_u32
            atomicAdd(&lh[i0 + 1], w1);
        }
    }
    __syncthreads();

    unsigned int* grow = fineg + (size_t)row * FW;
    for (int i = threadIdx.x; i < FW; i += 256) {
        const unsigned int v = lh[i];
        if (v) atomicAdd(&grow[i], v);              // native global u32 atomic
    }
}

// ---- Phase B: windowed Gaussian convolution + per-halfbatch score ------
// 16 blocks = (batch 0..7) x (half 0..1); 15 bins/block, 16 threads/bin.
__global__ __launch_bounds__(256) void hsim_scorepart_kernel(
    const unsigned int* __restrict__ fineg, float* __restrict__ partials,
    int lgF)
{
    const int F  = 1 << lgF;
    const int FW = F + 2;
    const int batch = blockIdx.x >> 1;
    const int half  = blockIdx.x & 1;

    const unsigned int* fp = fineg + (size_t)batch * FW;
    const unsigned int* ft = fineg + (size_t)(batch + 8) * FW;

    const int t    = threadIdx.x;
    const int binl = t >> 4;         // 0..15 (15 used)
    const int sub  = t & 15;

    __shared__ float sbin[16];
    if (t < 16) sbin[t] = 0.0f;
    __syncthreads();

    if (binl < 15) {
        const int   bin  = half * 15 + binl;
        const float c    = (bin + 0.5f) / 30.0f;
        const float Ff   = (float)F;
        const float invF = 1.0f / Ff;

        int ilo = (int)ceilf((c - RAD) * Ff + 0.5f);
        int ihi = (int)floorf((c + RAD) * Ff + 0.5f);
        ilo = max(ilo, 0);
        ihi = min(ihi, F + 1);

        float pw = 0.0f, tw = 0.0f;
        for (int f = ilo + sub; f <= ihi; f += 16) {
            const float x = ((float)f - 0.5f) * invF;   // fine-bin center
            const float d = x - c;
            const float e = __builtin_amdgcn_exp2f(KXF * d * d);
            pw = fmaf(e, (float)fp[f], pw);
            tw = fmaf(e, (float)ft[f], tw);
        }
#pragma unroll
        for (int off = 8; off >= 1; off >>= 1) {
            pw += __shfl_xor(pw, off, 64);
            tw += __shfl_xor(tw, off, 64);
        }
        if (sub == 0) {
            pw *= INV_SCALE;
            tw *= INV_SCALE;
            const float m  = fminf(pw, tw);
            const float pd = (pw == 0.0f) ? 1.0f : pw;
            sbin[binl] = m / pd;
        }
    }
    __syncthreads();

    if (t < 16) {
        float v = sbin[t];
#pragma unroll
        for (int off = 8; off >= 1; off >>= 1)
            v += __shfl_xor(v, off, 16);
        if (t == 0) partials[blockIdx.x] = v;
    }
}

// ---- Phase C: final sum --------------------------------------------------
__global__ __launch_bounds__(64) void hsim_final_kernel(
    const float* __restrict__ partials, float* __restrict__ out)
{
    const int t = threadIdx.x;
    float v = (t < 16) ? partials[t] : 0.0f;
#pragma unroll
    for (int off = 32; off >= 1; off >>= 1)
        v += __shfl_xor(v, off, 64);
    if (t == 0) out[0] = v * (1.0f / (float)NB);
}

extern "C" void kernel_launch(void* const* d_in, const int* in_sizes, int n_in,
                              void* d_out, int out_size, void* d_ws, size_t ws_size,
                              hipStream_t stream) {
    const float*  pred   = (const float*)d_in[0];
    const float*  target = (const float*)d_in[1];
    unsigned int* fineg  = (unsigned int*)d_ws;
    float*        out    = (float*)d_out;

    // Fine resolution by available scratch (ws_size fixed -> deterministic).
    int lgF = 11;                                                   // 131.3 KB
    if (ws_size < (size_t)NROWS * ((1 << 11) + 2) * 4 + 128) lgF = 9;  // 33 KB
    const int FW = (1 << lgF) + 2;

    float* partials = (float*)(fineg + (size_t)NROWS * FW);   // 16 floats

    hipMemsetAsync(fineg, 0, (size_t)NROWS * FW * sizeof(unsigned int), stream);
    hsim_fine_kernel<<<NROWS * BPR_A, 256, FW * sizeof(unsigned int), stream>>>(
        pred, target, fineg, lgF);
    hsim_scorepart_kernel<<<16, 256, 0, stream>>>(fineg, partials, lgF);
    hsim_final_kernel<<<1, 64, 0, stream>>>(partials, out);
}

// Round 7
// 31.892 us; speedup vs baseline: 2.8752x; 1.1630x over previous
//
#include <hip/hip_runtime.h>

// Problem constants (fixed by reference): pred/target (8,3,224,224) fp32.
#define BINS   30
#define NB     240               // 8 batches * 30 bins
#define ROW_N  150528            // 3*224*224 elements per batch row
#define ROW_N4 37632             // float4 per row
#define NROWS  16                // 2 inputs * 8 batches
#define LGF    11
#define FBINS  (1 << LGF)        // 2048 fine bins
#define FW     (FBINS + 2)       // + edge bins

// exp(-0.5*((x-c)/delta)^2) = exp2(KXF*(x-c)^2), KXF = -0.5*log2(e)*900
#define KXF (-649.2627684000335f)
#define RAD (6.5f / 30.0f)       // truncate kernel at |u| > 6.5 (tail < 7e-10)
#define MAGIC 0x5A17CAFEu

// Single dispatch, non-cooperative:
//  A) per-block LDS fine histogram of its chunk (native u32 LDS atomics)
//  B) per-block local convolution -> 30 coarse-bin partials (float)
//  C) store partials to private slot (atomicExch, device scope) + MAGIC flag
//  D) block 0 polls flags, reduces partials, computes score, writes out.
// No zero-init needed anywhere (stores only), so no memset dispatch.
// Score is invariant to the 16384x fixed-point scale (min(p,t)/p).
__global__ __launch_bounds__(256) void hsim_onepass(
    const float* __restrict__ pred,
    const float* __restrict__ target,
    unsigned int* __restrict__ partials,   // [G][32] float-bits
    unsigned int* __restrict__ flags,      // [G]
    float* __restrict__ out, int lgCPR)
{
    const int CPR   = 1 << lgCPR;          // chunks per row
    const int G     = NROWS << lgCPR;      // grid size
    const int row   = blockIdx.x >> lgCPR;
    const int chunk = blockIdx.x & (CPR - 1);
    const int input_sel = row >> 3;        // 0 = pred, 1 = target
    const int batch     = row & 7;
    const int t = threadIdx.x;

    __shared__ unsigned int lh[FW];
    __shared__ float sws[4];

    const float4* src4 =
        (const float4*)((input_sel ? target : pred) + (size_t)batch * ROW_N);

    for (int i = t; i < FW; i += 256) lh[i] = 0u;
    __syncthreads();

    // ---- A: linear-interpolated fine histogram, fixed-point weights -----
    const int stride = CPR << 8;
    const float Ff = (float)FBINS;
#pragma unroll 2
    for (int i = (chunk << 8) + t; i < ROW_N4; i += stride) {
        float4 v = src4[i];
        float xs[4] = { v.x, v.y, v.z, v.w };
#pragma unroll
        for (int k = 0; k < 4; ++k) {
            const float q  = fmaf(xs[k], Ff, -0.5f);
            const float fi = floorf(q);
            const unsigned int w1 = (unsigned int)((q - fi) * 16384.0f + 0.5f);
            const int i0 = (int)fi + 1;          // in [0, FBINS]
            atomicAdd(&lh[i0],     16384u - w1); // native ds_add_u32
            atomicAdd(&lh[i0 + 1], w1);
        }
    }
    __syncthreads();

    // ---- B: local windowed Gaussian convolution to 30 bins --------------
    const int bin = t >> 3;                 // 0..31 (30 used)
    const int sub = t & 7;
    if (bin < BINS) {
        const float c = (bin + 0.5f) * (1.0f / 30.0f);
        int ilo = (int)ceilf((c - RAD) * Ff + 0.5f);
        int ihi = (int)floorf((c + RAD) * Ff + 0.5f);
        ilo = max(ilo, 0);
        ihi = min(ihi, FBINS + 1);
        const float invF = 1.0f / Ff;

        float conv = 0.0f;
        for (int f = ilo + sub; f <= ihi; f += 8) {
            const float x = ((float)f - 0.5f) * invF;   // fine-bin center
            const float d = x - c;
            conv = fmaf(__builtin_amdgcn_exp2f(KXF * d * d), (float)lh[f], conv);
        }
        conv += __shfl_xor(conv, 1, 64);
        conv += __shfl_xor(conv, 2, 64);
        conv += __shfl_xor(conv, 4, 64);
        if (sub == 0)   // C: device-scope coherent store of this partial
            atomicExch(&partials[(blockIdx.x << 5) + bin], __float_as_uint(conv));
    }
    __syncthreads();                        // drains the exchanges (vmcnt)
    if (t == 0) {
        __threadfence();
        atomicExch(&flags[blockIdx.x], MAGIC);
    }

    if (blockIdx.x != 0) return;

    // ---- D: closer (block 0) --------------------------------------------
    for (int j = t; j < G; j += 256)
        while (atomicAdd(&flags[j], 0u) != MAGIC)
            __builtin_amdgcn_s_sleep(2);
    __syncthreads();
    __threadfence();

    float term = 0.0f;
    if (t < NB) {
        const int b = t / BINS;
        const int k = t - b * BINS;
        float p = 0.0f, tg = 0.0f;
        for (int c2 = 0; c2 < CPR; ++c2) {
            p  += __uint_as_float(
                    atomicAdd(&partials[((((b    ) << lgCPR) + c2) << 5) + k], 0u));
            tg += __uint_as_float(
                    atomicAdd(&partials[((((b + 8) << lgCPR) + c2) << 5) + k], 0u));
        }
        const float m = fminf(p, tg);
        term = (p == 0.0f) ? 0.0f : m / p;   // == min(p,t)/(p+mask) of ref
    }
#pragma unroll
    for (int off = 32; off >= 1; off >>= 1)
        term += __shfl_xor(term, off, 64);
    if ((t & 63) == 0) sws[t >> 6] = term;
    __syncthreads();
    if (t == 0)
        out[0] = (sws[0] + sws[1] + sws[2] + sws[3]) * (1.0f / (float)NB);
}

extern "C" void kernel_launch(void* const* d_in, const int* in_sizes, int n_in,
                              void* d_out, int out_size, void* d_ws, size_t ws_size,
                              hipStream_t stream) {
    const float* pred   = (const float*)d_in[0];
    const float* target = (const float*)d_in[1];

    // chunks-per-row by available scratch (ws_size fixed -> deterministic)
    int lgCPR = 5;                                         // 512 blocks, 67.6 KB
    {
        const size_t need = ((size_t)(NROWS << 5) * 32 + (NROWS << 5)) * 4;
        if (ws_size < need + 64) lgCPR = 3;                // 128 blocks, 16.9 KB
    }
    const int G = NROWS << lgCPR;

    unsigned int* partials = (unsigned int*)d_ws;          // [G][32]
    unsigned int* flags    = partials + (size_t)G * 32;    // [G]

    hsim_onepass<<<G, 256, 0, stream>>>(pred, target, partials, flags,
                                        (float*)d_out, lgCPR);
}

// Round 8
// 24.864 us; speedup vs baseline: 3.6879x; 1.2826x over previous
//
#include <hip/hip_runtime.h>

// Problem constants (fixed by reference): pred/target (8,3,224,224) fp32.
#define BINS   30
#define NB     240               // 8 batches * 30 bins
#define ROW_N  150528            // 3*224*224 elements per batch row
#define ROW_N4 37632             // float4 per row
#define NROWS  16                // 2 inputs * 8 batches
#define LGCPR  5                 // 32 chunks per row -> 512 blocks (all resident)
#define CPR    (1 << LGCPR)
#define G      (NROWS << LGCPR)
#define LGF    11
#define FBINS  (1 << LGF)        // 2048 fine bins
#define FW     (FBINS + 2)       // + edge bins

// exp(-0.5*((x-c)/delta)^2) = exp2(KXF*(x-c)^2), KXF = -0.5*log2(e)*900
#define KXF (-649.2627684000335f)
#define RAD (6.5f / 30.0f)       // truncate kernel at |u| > 6.5 (tail < 7e-10)
#define MAGIC 0x5A17CAFEu

// d_ws layout (u32): ghist[480] | ready | counter
// One dispatch. Block 0 zeroes ghist+counter, fences, sets ready=MAGIC.
// Every block: LDS fine hist -> local conv to 30 u32 partials -> (after
// ready==MAGIC) 30 fire-and-forget global u32 atomicAdds -> ticket++.
// Last ticket holder reduces the 480-word ghist (2 atomic loads/thread),
// writes the score, and clears ready so the next replay re-initializes.
// u32 accumulation is order-independent -> bit-deterministic per replay.
__global__ __launch_bounds__(256) void hsim_onepass(
    const float* __restrict__ pred,
    const float* __restrict__ target,
    unsigned int* __restrict__ ghist,     // [2*NB]
    unsigned int* __restrict__ ready,
    unsigned int* __restrict__ counter,
    float* __restrict__ out)
{
    const int row   = blockIdx.x >> LGCPR;
    const int chunk = blockIdx.x & (CPR - 1);
    const int input_sel = row >> 3;        // 0 = pred, 1 = target
    const int batch     = row & 7;
    const int t = threadIdx.x;

    __shared__ unsigned int lh[FW];
    __shared__ float sws[4];
    __shared__ int   s_is_closer;

    // ---- block 0: initialize accumulators, then release everyone --------
    if (blockIdx.x == 0) {
        for (int i = t; i < 2 * NB; i += 256) ghist[i] = 0u;
        if (t == 0) *counter = 0u;
        __syncthreads();
        if (t == 0) {
            __threadfence();
            atomicExch(ready, MAGIC);
        }
    }

    const float4* src4 =
        (const float4*)((input_sel ? target : pred) + (size_t)batch * ROW_N);

    for (int i = t; i < FW; i += 256) lh[i] = 0u;
    __syncthreads();

    // ---- A: linear-interpolated fine histogram (native LDS u32 atomics) -
    const float Ff = (float)FBINS;
#pragma unroll 2
    for (int i = (chunk << 8) + t; i < ROW_N4; i += (CPR << 8)) {
        float4 v = src4[i];
        float xs[4] = { v.x, v.y, v.z, v.w };
#pragma unroll
        for (int k = 0; k < 4; ++k) {
            const float q  = fmaf(xs[k], Ff, -0.5f);
            const float fi = floorf(q);
            const unsigned int w1 = (unsigned int)((q - fi) * 16384.0f + 0.5f);
            const int i0 = (int)fi + 1;          // in [0, FBINS]
            atomicAdd(&lh[i0],     16384u - w1); // ds_add_u32
            atomicAdd(&lh[i0 + 1], w1);
        }
    }
    __syncthreads();

    // ---- wait for init (normally already done) --------------------------
    if (t == 0)
        while (atomicAdd(ready, 0u) != MAGIC)
            __builtin_amdgcn_s_sleep(2);
    __syncthreads();

    // ---- B: local windowed Gaussian conv -> 30 u32 partials -> global ---
    const int bin = t >> 3;                 // 0..31 (30 used)
    const int sub = t & 7;
    if (bin < BINS) {
        const float c = (bin + 0.5f) * (1.0f / 30.0f);
        int ilo = (int)ceilf((c - RAD) * Ff + 0.5f);
        int ihi = (int)floorf((c + RAD) * Ff + 0.5f);
        ilo = max(ilo, 0);
        ihi = min(ihi, FBINS + 1);
        const float invF = 1.0f / Ff;

        float conv = 0.0f;
        for (int f = ilo + sub; f <= ihi; f += 8) {
            const float x = ((float)f - 0.5f) * invF;   // fine-bin center
            const float d = x - c;
            conv = fmaf(__builtin_amdgcn_exp2f(KXF * d * d), (float)lh[f], conv);
        }
        conv += __shfl_xor(conv, 1, 64);
        conv += __shfl_xor(conv, 2, 64);
        conv += __shfl_xor(conv, 4, 64);
        if (sub == 0)   // fire-and-forget native u32 atomic (no return)
            atomicAdd(&ghist[row * BINS + bin], (unsigned int)(conv + 0.5f));
    }
    __syncthreads();

    // ---- ticket: last block becomes the closer --------------------------
    if (t == 0) {
        __threadfence();
        s_is_closer = (atomicAdd(counter, 1u) == G - 1u);
    }
    __syncthreads();
    if (!s_is_closer) return;
    __threadfence();

    // ---- closer: 480 coherent loads total, score, write, cleanup --------
    float term = 0.0f;
    if (t < NB) {
        const float p  = (float)atomicAdd(&ghist[t], 0u);        // pred rows
        const float tg = (float)atomicAdd(&ghist[NB + t], 0u);   // target rows
        term = (p == 0.0f) ? 0.0f : fminf(p, tg) / p;
    }
#pragma unroll
    for (int off = 32; off >= 1; off >>= 1)
        term += __shfl_xor(term, off, 64);
    if ((t & 63) == 0) sws[t >> 6] = term;
    __syncthreads();
    if (t == 0) {
        out[0] = (sws[0] + sws[1] + sws[2] + sws[3]) * (1.0f / (float)NB);
        __threadfence();
        atomicExch(ready, 0u);   // next replay re-initializes
    }
}

extern "C" void kernel_launch(void* const* d_in, const int* in_sizes, int n_in,
                              void* d_out, int out_size, void* d_ws, size_t ws_size,
                              hipStream_t stream) {
    const float* pred   = (const float*)d_in[0];
    const float* target = (const float*)d_in[1];

    unsigned int* ghist   = (unsigned int*)d_ws;   // 480 u32
    unsigned int* ready   = ghist + 2 * NB;
    unsigned int* counter = ready + 1;

    hsim_onepass<<<G, 256, 0, stream>>>(pred, target, ghist, ready, counter,
                                        (float*)d_out);
}